// Round 2
// baseline (10010.525 us; speedup 1.0000x reference)
//
#include <hip/hip_runtime.h>
#include <math.h>
#include <stdint.h>

#define BM 64
#define BN 256
#define BK 16
#define NT 256

union F4 { float4 v; float f[4]; };

// ---------------------------------------------------------------------------
// fp32 GEMM core: C[64 x 256] tile, A row-major [M,K] (lda), B row-major [K,N]
// (ldb), 256 threads, per-thread 4 rows x 16 cols.
// A staged transposed+XOR-swizzled in LDS ([k][m] with m-group ^ k), B linear.
// ---------------------------------------------------------------------------
__device__ __forceinline__ void compute_tile(const float* As, const float* Bs,
                                             float acc[4][16], int ty, int tx) {
#pragma unroll
  for (int k = 0; k < BK; ++k) {
    F4 a; a.v = *(const float4*)(As + k * 64 + ((ty ^ k) & 15) * 4);
    F4 b[4];
#pragma unroll
    for (int j = 0; j < 4; ++j)
      b[j].v = *(const float4*)(Bs + k * BN + tx * 4 + 64 * j);
#pragma unroll
    for (int r = 0; r < 4; ++r)
#pragma unroll
      for (int j = 0; j < 4; ++j)
#pragma unroll
        for (int q = 0; q < 4; ++q)
          acc[r][j * 4 + q] += a.f[r] * b[j].f[q];
  }
}

__device__ __forceinline__ void gemm_core(const float* __restrict__ Ab, int lda,
                                          const float* __restrict__ Bb, int ldb,
                                          int K, float acc[4][16], int tid,
                                          float* As, float* Bs) {
  const int m = tid >> 2, k0 = (tid & 3) * 4;
  const int kb = tid >> 6, n0 = (tid & 63) * 4;
  F4 areg; F4 breg[4];
  areg.v = *(const float4*)(Ab + (size_t)m * lda + k0);
#pragma unroll
  for (int r = 0; r < 4; ++r)
    breg[r].v = *(const float4*)(Bb + (size_t)(kb + 4 * r) * ldb + n0);
  const int nt = K / BK;
  for (int kt = 0; kt < nt; ++kt) {
    __syncthreads();
#pragma unroll
    for (int i = 0; i < 4; ++i) {
      int k = k0 + i;
      As[k * 64 + (((m >> 2) ^ k) & 15) * 4 + (m & 3)] = areg.f[i];
    }
#pragma unroll
    for (int r = 0; r < 4; ++r)
      *(float4*)(Bs + (kb + 4 * r) * BN + n0) = breg[r].v;
    __syncthreads();
    if (kt + 1 < nt) {
      int kg = (kt + 1) * BK;
      areg.v = *(const float4*)(Ab + (size_t)m * lda + kg + k0);
#pragma unroll
      for (int r = 0; r < 4; ++r)
        breg[r].v = *(const float4*)(Bb + (size_t)(kg + kb + 4 * r) * ldb + n0);
    }
    compute_tile(As, Bs, acc, tid >> 4, tid & 15);
  }
}

__device__ __forceinline__ void reduce16(float& s, float& s2) {
#pragma unroll
  for (int msk = 1; msk < 16; msk <<= 1) {
    s  += __shfl_xor(s,  msk, 64);
    s2 += __shfl_xor(s2, msk, 64);
  }
}

__device__ __forceinline__ float silu_f(float x) { return x / (1.f + expf(-x)); }
__device__ __forceinline__ float gelu_f(float x) {
  return 0.5f * x * (1.f + erff(x * 0.70710678118654752f));
}

// K1: H1[:,0:512) = silu(X @ fw_w1 + fw_b1); H1[:,512:1024) = silu(X @ bw_w1 + bw_b1)
__global__ __launch_bounds__(NT) void k_lin1(const float* __restrict__ X,
    const float* __restrict__ fw1, const float* __restrict__ bw1,
    const float* __restrict__ fb1, const float* __restrict__ bb1,
    float* __restrict__ H1) {
  __shared__ float As[BK * BM];
  __shared__ float Bs[BK * BN];
  const int tid = threadIdx.x;
  const int row0 = blockIdx.x * BM;
  const int by = blockIdx.y;  // 0..3
  const float* W    = ((by < 2) ? fw1 : bw1) + (by & 1) * 256;
  const float* bias = ((by < 2) ? fb1 : bb1) + (by & 1) * 256;
  float acc[4][16] = {};
  gemm_core(X + (size_t)row0 * 256, 256, W, 512, 256, acc, tid, As, Bs);
  const int tx = tid & 15, ty = tid >> 4;
  F4 b4[4];
#pragma unroll
  for (int j = 0; j < 4; ++j) b4[j].v = *(const float4*)(bias + tx * 4 + 64 * j);
#pragma unroll
  for (int r = 0; r < 4; ++r) {
    size_t row = row0 + ty * 4 + r;
    float* orow = H1 + row * 1024 + by * 256 + tx * 4;
#pragma unroll
    for (int j = 0; j < 4; ++j) {
      F4 o;
#pragma unroll
      for (int q = 0; q < 4; ++q)
        o.f[q] = silu_f(acc[r][j * 4 + q] + b4[j].f[q]);
      *(float4*)(orow + 64 * j) = o.v;
    }
  }
}

// K2: F[:,0:256) = LN(H1[:,0:512)@fw_w2+fw_b2); F[:,256:512) = LN(H1[:,512:)@bw_w2+bw_b2)
__global__ __launch_bounds__(NT) void k_lin2ln(const float* __restrict__ H1,
    const float* __restrict__ fw2, const float* __restrict__ bw2,
    const float* __restrict__ fb2, const float* __restrict__ bb2,
    const float* __restrict__ flw, const float* __restrict__ flb,
    const float* __restrict__ blw, const float* __restrict__ blb,
    float* __restrict__ F) {
  __shared__ float As[BK * BM];
  __shared__ float Bs[BK * BN];
  const int tid = threadIdx.x;
  const int row0 = blockIdx.x * BM;
  const int by = blockIdx.y;  // 0..1
  const float* W    = by ? bw2 : fw2;
  const float* bias = by ? bb2 : fb2;
  const float* lw   = by ? blw : flw;
  const float* lb   = by ? blb : flb;
  float acc[4][16] = {};
  gemm_core(H1 + (size_t)row0 * 1024 + by * 512, 1024, W, 256, 512, acc, tid, As, Bs);
  const int tx = tid & 15, ty = tid >> 4;
  F4 b4[4], w4[4], lb4[4];
#pragma unroll
  for (int j = 0; j < 4; ++j) {
    b4[j].v  = *(const float4*)(bias + tx * 4 + 64 * j);
    w4[j].v  = *(const float4*)(lw + tx * 4 + 64 * j);
    lb4[j].v = *(const float4*)(lb + tx * 4 + 64 * j);
  }
#pragma unroll
  for (int r = 0; r < 4; ++r) {
    float vv[16];
    float s = 0.f, s2 = 0.f;
#pragma unroll
    for (int t = 0; t < 16; ++t) {
      float v = acc[r][t] + b4[t >> 2].f[t & 3];
      vv[t] = v; s += v; s2 += v * v;
    }
    reduce16(s, s2);
    float mu = s * (1.f / 256.f);
    float rs = rsqrtf(s2 * (1.f / 256.f) - mu * mu + 1e-5f);
    size_t row = row0 + ty * 4 + r;
    float* orow = F + row * 512 + by * 256 + tx * 4;
#pragma unroll
    for (int j = 0; j < 4; ++j) {
      F4 o;
#pragma unroll
      for (int q = 0; q < 4; ++q)
        o.f[q] = (vv[j * 4 + q] - mu) * rs * w4[j].f[q] + lb4[j].f[q];
      *(float4*)(orow + 64 * j) = o.v;
    }
  }
}

// K3: M = F@mg_w+mg_b; Xc = LN(Xin+M, nm); Hb = LN(Xc, ffn_ln)
__global__ __launch_bounds__(NT) void k_merge(const float* __restrict__ Fb,
    const float* __restrict__ mgw, const float* __restrict__ mgb,
    const float* __restrict__ Xin,
    const float* __restrict__ nmw, const float* __restrict__ nmb,
    const float* __restrict__ flw, const float* __restrict__ flb,
    float* __restrict__ Xc, float* __restrict__ Hb) {
  __shared__ float As[BK * BM];
  __shared__ float Bs[BK * BN];
  const int tid = threadIdx.x;
  const int row0 = blockIdx.x * BM;
  float acc[4][16] = {};
  gemm_core(Fb + (size_t)row0 * 512, 512, mgw, 256, 512, acc, tid, As, Bs);
  const int tx = tid & 15, ty = tid >> 4;
  F4 b4[4], nw4[4], nb4[4], fw4[4], fb4[4];
#pragma unroll
  for (int j = 0; j < 4; ++j) {
    b4[j].v  = *(const float4*)(mgb + tx * 4 + 64 * j);
    nw4[j].v = *(const float4*)(nmw + tx * 4 + 64 * j);
    nb4[j].v = *(const float4*)(nmb + tx * 4 + 64 * j);
    fw4[j].v = *(const float4*)(flw + tx * 4 + 64 * j);
    fb4[j].v = *(const float4*)(flb + tx * 4 + 64 * j);
  }
#pragma unroll
  for (int r = 0; r < 4; ++r) {
    size_t row = row0 + ty * 4 + r;
    float vv[16];
    float s = 0.f, s2 = 0.f;
#pragma unroll
    for (int j = 0; j < 4; ++j) {
      F4 xr; xr.v = *(const float4*)(Xin + row * 256 + tx * 4 + 64 * j);
#pragma unroll
      for (int q = 0; q < 4; ++q) {
        float v = acc[r][j * 4 + q] + b4[j].f[q] + xr.f[q];
        vv[j * 4 + q] = v; s += v; s2 += v * v;
      }
    }
    reduce16(s, s2);
    float mu = s * (1.f / 256.f);
    float rs = rsqrtf(s2 * (1.f / 256.f) - mu * mu + 1e-5f);
    float xv[16];
    float t = 0.f, t2 = 0.f;
#pragma unroll
    for (int j = 0; j < 4; ++j) {
      F4 o;
#pragma unroll
      for (int q = 0; q < 4; ++q) {
        float x = (vv[j * 4 + q] - mu) * rs * nw4[j].f[q] + nb4[j].f[q];
        xv[j * 4 + q] = x; t += x; t2 += x * x;
        o.f[q] = x;
      }
      *(float4*)(Xc + row * 256 + tx * 4 + 64 * j) = o.v;
    }
    reduce16(t, t2);
    float mu2 = t * (1.f / 256.f);
    float rs2 = rsqrtf(t2 * (1.f / 256.f) - mu2 * mu2 + 1e-5f);
#pragma unroll
    for (int j = 0; j < 4; ++j) {
      F4 o;
#pragma unroll
      for (int q = 0; q < 4; ++q)
        o.f[q] = (xv[j * 4 + q] - mu2) * rs2 * fw4[j].f[q] + fb4[j].f[q];
      *(float4*)(Hb + row * 256 + tx * 4 + 64 * j) = o.v;
    }
  }
}

// K4: Ab = gelu(Hb @ ffn_w1 + ffn_b1)   (N = 1024, 4 block-cols)
__global__ __launch_bounds__(NT) void k_ffn1(const float* __restrict__ Hb,
    const float* __restrict__ W1, const float* __restrict__ B1,
    float* __restrict__ Ab) {
  __shared__ float As[BK * BM];
  __shared__ float Bs[BK * BN];
  const int tid = threadIdx.x;
  const int row0 = blockIdx.x * BM;
  const int by = blockIdx.y;  // 0..3
  float acc[4][16] = {};
  gemm_core(Hb + (size_t)row0 * 256, 256, W1 + by * 256, 1024, 256, acc, tid, As, Bs);
  const int tx = tid & 15, ty = tid >> 4;
  F4 b4[4];
#pragma unroll
  for (int j = 0; j < 4; ++j)
    b4[j].v = *(const float4*)(B1 + by * 256 + tx * 4 + 64 * j);
#pragma unroll
  for (int r = 0; r < 4; ++r) {
    size_t row = row0 + ty * 4 + r;
    float* orow = Ab + row * 1024 + by * 256 + tx * 4;
#pragma unroll
    for (int j = 0; j < 4; ++j) {
      F4 o;
#pragma unroll
      for (int q = 0; q < 4; ++q)
        o.f[q] = gelu_f(acc[r][j * 4 + q] + b4[j].f[q]);
      *(float4*)(orow + 64 * j) = o.v;
    }
  }
}

// K5: Xout = (Xc + Ab @ ffn_w2 + ffn_b2) * mask
__global__ __launch_bounds__(NT) void k_ffn2(const float* __restrict__ Ab,
    const float* __restrict__ W2, const float* __restrict__ B2,
    const float* __restrict__ Xc, const float* __restrict__ mask,
    float* __restrict__ Xout) {
  __shared__ float As[BK * BM];
  __shared__ float Bs[BK * BN];
  const int tid = threadIdx.x;
  const int row0 = blockIdx.x * BM;
  float acc[4][16] = {};
  gemm_core(Ab + (size_t)row0 * 1024, 1024, W2, 256, 1024, acc, tid, As, Bs);
  const int tx = tid & 15, ty = tid >> 4;
  F4 b4[4];
#pragma unroll
  for (int j = 0; j < 4; ++j)
    b4[j].v = *(const float4*)(B2 + tx * 4 + 64 * j);
#pragma unroll
  for (int r = 0; r < 4; ++r) {
    size_t row = row0 + ty * 4 + r;
    float mk = mask[row];
#pragma unroll
    for (int j = 0; j < 4; ++j) {
      F4 xr; xr.v = *(const float4*)(Xc + row * 256 + tx * 4 + 64 * j);
      F4 o;
#pragma unroll
      for (int q = 0; q < 4; ++q)
        o.f[q] = (acc[r][j * 4 + q] + b4[j].f[q] + xr.f[q]) * mk;
      *(float4*)(Xout + row * 256 + tx * 4 + 64 * j) = o.v;
    }
  }
}

extern "C" void kernel_launch(void* const* d_in, const int* in_sizes, int n_in,
                              void* d_out, int out_size, void* d_ws, size_t ws_size,
                              hipStream_t stream) {
  const float* slots  = (const float*)d_in[0];
  const float* keep   = (const float*)d_in[1];
  const float* fw_w1  = (const float*)d_in[2];
  const float* fw_b1  = (const float*)d_in[3];
  const float* fw_w2  = (const float*)d_in[4];
  const float* fw_b2  = (const float*)d_in[5];
  const float* fw_lnw = (const float*)d_in[6];
  const float* fw_lnb = (const float*)d_in[7];
  const float* bw_w1  = (const float*)d_in[8];
  const float* bw_b1  = (const float*)d_in[9];
  const float* bw_w2  = (const float*)d_in[10];
  const float* bw_b2  = (const float*)d_in[11];
  const float* bw_lnw = (const float*)d_in[12];
  const float* bw_lnb = (const float*)d_in[13];
  const float* mg_w   = (const float*)d_in[14];
  const float* mg_b   = (const float*)d_in[15];
  const float* nm_w   = (const float*)d_in[16];
  const float* nm_b   = (const float*)d_in[17];
  const float* ffn_lnw= (const float*)d_in[18];
  const float* ffn_lnb= (const float*)d_in[19];
  const float* ffn_w1 = (const float*)d_in[20];
  const float* ffn_b1 = (const float*)d_in[21];
  const float* ffn_w2 = (const float*)d_in[22];
  const float* ffn_b2 = (const float*)d_in[23];
  (void)n_in; (void)out_size;

  const int N = in_sizes[0] / 256;  // 131072 tokens
  float* out = (float*)d_out;
  float* ws  = (float*)d_ws;

  // pick the largest power-of-two chunk whose scratch fits in ws
  size_t wsf = ws_size / sizeof(float);
  int chunk = N;
  while ((size_t)chunk * 2048 > wsf && chunk > 64) chunk >>= 1;

  float* H1 = ws;                              // chunk*1024 (aliased as Ab)
  float* F  = ws + (size_t)chunk * 1024;       // chunk*512
  float* Xc = F  + (size_t)chunk * 512;        // chunk*256
  float* Hb = Xc + (size_t)chunk * 256;        // chunk*256
  float* Ab = H1;

  for (int layer = 0; layer < 2; ++layer) {
    const float* Xsrc = (layer == 0) ? slots : out;  // d_out doubles as inter-layer buf
    float* Xdst = out;
    const float* w_fw1 = fw_w1 + (size_t)layer * 256 * 512;
    const float* b_fw1 = fw_b1 + (size_t)layer * 512;
    const float* w_fw2 = fw_w2 + (size_t)layer * 512 * 256;
    const float* b_fw2 = fw_b2 + (size_t)layer * 256;
    const float* w_flw = fw_lnw + (size_t)layer * 256;
    const float* w_flb = fw_lnb + (size_t)layer * 256;
    const float* w_bw1 = bw_w1 + (size_t)layer * 256 * 512;
    const float* b_bw1 = bw_b1 + (size_t)layer * 512;
    const float* w_bw2 = bw_w2 + (size_t)layer * 512 * 256;
    const float* b_bw2 = bw_b2 + (size_t)layer * 256;
    const float* w_blw = bw_lnw + (size_t)layer * 256;
    const float* w_blb = bw_lnb + (size_t)layer * 256;
    const float* w_mg  = mg_w + (size_t)layer * 512 * 256;
    const float* b_mg  = mg_b + (size_t)layer * 256;
    const float* w_nmw = nm_w + (size_t)layer * 256;
    const float* w_nmb = nm_b + (size_t)layer * 256;
    const float* w_fln = ffn_lnw + (size_t)layer * 256;
    const float* b_fln = ffn_lnb + (size_t)layer * 256;
    const float* w_f1  = ffn_w1 + (size_t)layer * 256 * 1024;
    const float* b_f1  = ffn_b1 + (size_t)layer * 1024;
    const float* w_f2  = ffn_w2 + (size_t)layer * 1024 * 256;
    const float* b_f2  = ffn_b2 + (size_t)layer * 256;

    for (int c0 = 0; c0 < N; c0 += chunk) {
      const float* Xi = Xsrc + (size_t)c0 * 256;
      dim3 blk(NT);
      dim3 g4(chunk / BM, 4), g2(chunk / BM, 2), g1(chunk / BM, 1);
      k_lin1<<<g4, blk, 0, stream>>>(Xi, w_fw1, w_bw1, b_fw1, b_bw1, H1);
      k_lin2ln<<<g2, blk, 0, stream>>>(H1, w_fw2, w_bw2, b_fw2, b_bw2,
                                       w_flw, w_flb, w_blw, w_blb, F);
      k_merge<<<g1, blk, 0, stream>>>(F, w_mg, b_mg, Xi, w_nmw, w_nmb,
                                      w_fln, b_fln, Xc, Hb);
      k_ffn1<<<g4, blk, 0, stream>>>(Hb, w_f1, b_f1, Ab);
      k_ffn2<<<g1, blk, 0, stream>>>(Ab, w_f2, b_f2, Xc, keep + c0,
                                     Xdst + (size_t)c0 * 256);
    }
  }
}

// Round 3
// 3890.352 us; speedup vs baseline: 2.5732x; 2.5732x over previous
//
#include <hip/hip_runtime.h>
#include <math.h>
#include <stdint.h>

typedef __attribute__((ext_vector_type(8))) short bf16x8;
typedef __attribute__((ext_vector_type(4))) float f32x4;

union BF8 { ushort u[8]; bf16x8 v; };

__device__ __forceinline__ void gll16(const void* g, void* l) {
  __builtin_amdgcn_global_load_lds(
      (const __attribute__((address_space(1))) uint32_t*)g,
      (__attribute__((address_space(3))) uint32_t*)l, 16, 0, 0);
}

__device__ __forceinline__ void split_bf(float x, ushort& h, ushort& lo) {
  uint b = __float_as_uint(x);
  h = (ushort)(b >> 16);
  float hf = __uint_as_float((uint)h << 16);
  lo = (ushort)(__float_as_uint(x - hf) >> 16);
}
__device__ __forceinline__ float join_bf(ushort h, ushort l) {
  return __uint_as_float((uint)h << 16) + __uint_as_float((uint)l << 16);
}

#define EPI_RAW 0
#define EPI_SILU 1
#define EPI_GELU 2
#define EPI_RES 3

// ---------------------------------------------------------------------------
// MFMA GEMM: C[128 x 128] block tile, 4 waves (2x2), wave tile 64x64 as 4x4
// fragments of v_mfma_f32_16x16x32_bf16. 3-term split-bf16 (hi/lo) for fp32
// accuracy. A: hi/lo bf16 planes [M][lda] (or fp32 with in-kernel split when
// AF32). B: pre-transposed hi/lo planes [NTOT][K]. Staging: per-lane
// fragment-gather global_load_lds -> LDS holds fragments in lane order ->
// ds_read_b128 at lane*16B, conflict-free.
// ---------------------------------------------------------------------------
template<int KSTEPS, int EPI, bool AF32>
__global__ __launch_bounds__(256) void k_gemm(
    const void* __restrict__ A0, const ushort* __restrict__ Alo, int lda,
    int bshift, int a_br_off,
    const ushort* __restrict__ Bhi, const ushort* __restrict__ Blo,
    const float* __restrict__ bias,
    void* __restrict__ out0, ushort* __restrict__ out_lo, int ldo,
    const float* __restrict__ resid, const float* __restrict__ kmask) {
  constexpr int K = KSTEPS * 32;
  __shared__ __align__(16) ushort lds[4][8][512];  // planes: Ahi, Alo, Bhi, Blo
  const int tid = threadIdx.x;
  const int lane = tid & 63;
  const int w = tid >> 6;
  const int row0 = blockIdx.x * 128;
  const int by = blockIdx.y;
  const int col0 = by * 128;
  const int aoff = (by >> bshift) * a_br_off;

  f32x4 acc[4][4];
#pragma unroll
  for (int i = 0; i < 4; ++i)
#pragma unroll
    for (int j = 0; j < 4; ++j) acc[i][j] = (f32x4){0.f, 0.f, 0.f, 0.f};

  const int lrow = lane & 15, lk8 = (lane >> 4) * 8;
  const size_t abase = (size_t)(row0 + lrow) * lda + aoff + lk8;
  const size_t bbase = (size_t)(col0 + lrow) * K + lk8;

  // per-wave plane source for hl staging
  const ushort* Ahi = (const ushort*)A0;
  const ushort* gsrc = (w == 0) ? Ahi + abase
                     : (w == 1) ? (AF32 ? Ahi + abase : Alo + abase)
                     : (w == 2) ? Bhi + bbase : Blo + bbase;
  const int st16 = (w < 2) ? 16 * lda : 16 * K;
  const float* Af = (const float*)A0;

  auto stage_hl = [&](int s) {
    const ushort* p = gsrc + (size_t)s * 32;
#pragma unroll
    for (int i = 0; i < 8; ++i)
      gll16(p + (size_t)i * st16, &lds[w][i][0]);
  };
  auto stage_af32 = [&](int s) {
#pragma unroll
    for (int t = 0; t < 2; ++t) {
      int i = w + t * 4;
      gll16(Bhi + bbase + (size_t)i * 16 * K + s * 32, &lds[2][i][0]);
      gll16(Blo + bbase + (size_t)i * 16 * K + s * 32, &lds[3][i][0]);
    }
#pragma unroll
    for (int t = 0; t < 2; ++t) {
      int c = tid + t * 256;
      int rb = c >> 6, cl = c & 63;
      int row = rb * 16 + (cl & 15), kk = (cl >> 4) * 8;
      const float* sp = Af + (size_t)(row0 + row) * lda + kk + s * 32;
      float4 x0 = *(const float4*)sp;
      float4 x1 = *(const float4*)(sp + 4);
      float xs[8] = {x0.x, x0.y, x0.z, x0.w, x1.x, x1.y, x1.z, x1.w};
      BF8 h, l;
#pragma unroll
      for (int e = 0; e < 8; ++e) split_bf(xs[e], h.u[e], l.u[e]);
      *(bf16x8*)&lds[0][rb][cl * 8] = h.v;
      *(bf16x8*)&lds[1][rb][cl * 8] = l.v;
    }
  };

  if (AF32) stage_af32(0); else stage_hl(0);

  const int wr = w >> 1, wc = w & 1;
#pragma unroll 1
  for (int s = 0; s < KSTEPS; ++s) {
    __syncthreads();  // staged data (vm + lgkm drained) visible in LDS
    bf16x8 ah[4], al[4], bh[4], bl[4];
#pragma unroll
    for (int f = 0; f < 4; ++f) {
      ah[f] = *(const bf16x8*)&lds[0][wr * 4 + f][lane * 8];
      al[f] = *(const bf16x8*)&lds[1][wr * 4 + f][lane * 8];
      bh[f] = *(const bf16x8*)&lds[2][wc * 4 + f][lane * 8];
      bl[f] = *(const bf16x8*)&lds[3][wc * 4 + f][lane * 8];
    }
    __syncthreads();  // all reads done; safe to overwrite LDS
    if (s + 1 < KSTEPS) { if (AF32) stage_af32(s + 1); else stage_hl(s + 1); }
#pragma unroll
    for (int f = 0; f < 4; ++f)
#pragma unroll
      for (int g = 0; g < 4; ++g) {
        acc[f][g] = __builtin_amdgcn_mfma_f32_16x16x32_bf16(ah[f], bh[g], acc[f][g], 0, 0, 0);
        acc[f][g] = __builtin_amdgcn_mfma_f32_16x16x32_bf16(al[f], bh[g], acc[f][g], 0, 0, 0);
        acc[f][g] = __builtin_amdgcn_mfma_f32_16x16x32_bf16(ah[f], bl[g], acc[f][g], 0, 0, 0);
      }
  }

  // epilogue: C/D layout col = lane&15, row = (lane>>4)*4 + reg  [m89]
  const int rb0 = row0 + wr * 64 + ((lane >> 4) * 4);
  const int cb0 = col0 + wc * 64 + (lane & 15);
  float b4[4];
#pragma unroll
  for (int g = 0; g < 4; ++g) b4[g] = bias[cb0 + g * 16];
  ushort* oh = (ushort*)out0;
  float* of = (float*)out0;
#pragma unroll
  for (int f = 0; f < 4; ++f)
#pragma unroll
    for (int r = 0; r < 4; ++r) {
      int grow = rb0 + f * 16 + r;
      if (EPI == EPI_RES) {
        float mk = kmask[grow];
#pragma unroll
        for (int g = 0; g < 4; ++g) {
          int gc = cb0 + g * 16;
          float x = acc[f][g][r] + b4[g] + resid[(size_t)grow * 256 + gc];
          of[(size_t)grow * ldo + gc] = x * mk;
        }
      } else {
#pragma unroll
        for (int g = 0; g < 4; ++g) {
          float x = acc[f][g][r] + b4[g];
          if (EPI == EPI_SILU) x = x / (1.f + expf(-x));
          if (EPI == EPI_GELU) x = 0.5f * x * (1.f + erff(x * 0.70710678118654752f));
          ushort h, lo;
          split_bf(x, h, lo);
          oh[(size_t)grow * ldo + cb0 + g * 16] = h;
          out_lo[(size_t)grow * ldo + cb0 + g * 16] = lo;
        }
      }
    }
}

__device__ __forceinline__ void reduce16(float& s, float& s2) {
#pragma unroll
  for (int msk = 1; msk < 16; msk <<= 1) {
    s += __shfl_xor(s, msk, 64);
    s2 += __shfl_xor(s2, msk, 64);
  }
}

// LN over 256 cols of hl-plane input -> hl-plane output (per-branch params)
__global__ __launch_bounds__(256) void k_ln_hl(
    const ushort* __restrict__ Ih, const ushort* __restrict__ Il, int ldi,
    const float* __restrict__ flw, const float* __restrict__ flb,
    const float* __restrict__ blw, const float* __restrict__ blb,
    ushort* __restrict__ Oh, ushort* __restrict__ Ol, int ldo) {
  const int b = blockIdx.y;
  const int co = b * 256;
  const float* lw = b ? blw : flw;
  const float* lb = b ? blb : flb;
  const int tid = threadIdx.x, tx = tid & 15, ty = tid >> 4;
  const size_t row0 = (size_t)blockIdx.x * 64;
  float w16[16], b16[16];
#pragma unroll
  for (int t = 0; t < 16; ++t) {
    int c = tx * 4 + 64 * (t >> 2) + (t & 3);
    w16[t] = lw[c]; b16[t] = lb[c];
  }
  for (int r = 0; r < 4; ++r) {
    size_t row = row0 + ty * 4 + r;
    float v[16], s = 0.f, s2 = 0.f;
#pragma unroll
    for (int j = 0; j < 4; ++j) {
      ushort4 hv = *(const ushort4*)&Ih[row * ldi + co + tx * 4 + 64 * j];
      ushort4 lv = *(const ushort4*)&Il[row * ldi + co + tx * 4 + 64 * j];
      v[j * 4 + 0] = join_bf(hv.x, lv.x);
      v[j * 4 + 1] = join_bf(hv.y, lv.y);
      v[j * 4 + 2] = join_bf(hv.z, lv.z);
      v[j * 4 + 3] = join_bf(hv.w, lv.w);
#pragma unroll
      for (int q = 0; q < 4; ++q) { s += v[j * 4 + q]; s2 += v[j * 4 + q] * v[j * 4 + q]; }
    }
    reduce16(s, s2);
    float mu = s * (1.f / 256.f);
    float rs = rsqrtf(s2 * (1.f / 256.f) - mu * mu + 1e-5f);
#pragma unroll
    for (int j = 0; j < 4; ++j) {
      ushort4 ho, lo;
      ushort hh, ll;
      float y0 = (v[j * 4 + 0] - mu) * rs * w16[j * 4 + 0] + b16[j * 4 + 0];
      split_bf(y0, hh, ll); ho.x = hh; lo.x = ll;
      float y1 = (v[j * 4 + 1] - mu) * rs * w16[j * 4 + 1] + b16[j * 4 + 1];
      split_bf(y1, hh, ll); ho.y = hh; lo.y = ll;
      float y2 = (v[j * 4 + 2] - mu) * rs * w16[j * 4 + 2] + b16[j * 4 + 2];
      split_bf(y2, hh, ll); ho.z = hh; lo.z = ll;
      float y3 = (v[j * 4 + 3] - mu) * rs * w16[j * 4 + 3] + b16[j * 4 + 3];
      split_bf(y3, hh, ll); ho.w = hh; lo.w = ll;
      *(ushort4*)&Oh[row * ldo + co + tx * 4 + 64 * j] = ho;
      *(ushort4*)&Ol[row * ldo + co + tx * 4 + 64 * j] = lo;
    }
  }
}

// merge-post: v = M + X; Xc = LN(v,nm); Hb = LN(Xc, ffn_ln)   (all width 256)
__global__ __launch_bounds__(256) void k_mergepost(
    const ushort* __restrict__ Mh, const ushort* __restrict__ Ml,
    const float* __restrict__ Xin,
    const float* __restrict__ nmw, const float* __restrict__ nmb,
    const float* __restrict__ fw, const float* __restrict__ fb,
    float* __restrict__ Xc, ushort* __restrict__ Hbh, ushort* __restrict__ Hbl) {
  const int tid = threadIdx.x, tx = tid & 15, ty = tid >> 4;
  const size_t row0 = (size_t)blockIdx.x * 64;
  float nw16[16], nb16[16], fw16[16], fb16[16];
#pragma unroll
  for (int t = 0; t < 16; ++t) {
    int c = tx * 4 + 64 * (t >> 2) + (t & 3);
    nw16[t] = nmw[c]; nb16[t] = nmb[c]; fw16[t] = fw[c]; fb16[t] = fb[c];
  }
  for (int r = 0; r < 4; ++r) {
    size_t row = row0 + ty * 4 + r;
    float v[16], s = 0.f, s2 = 0.f;
#pragma unroll
    for (int j = 0; j < 4; ++j) {
      ushort4 hv = *(const ushort4*)&Mh[row * 256 + tx * 4 + 64 * j];
      ushort4 lv = *(const ushort4*)&Ml[row * 256 + tx * 4 + 64 * j];
      float4 xr = *(const float4*)&Xin[row * 256 + tx * 4 + 64 * j];
      v[j * 4 + 0] = join_bf(hv.x, lv.x) + xr.x;
      v[j * 4 + 1] = join_bf(hv.y, lv.y) + xr.y;
      v[j * 4 + 2] = join_bf(hv.z, lv.z) + xr.z;
      v[j * 4 + 3] = join_bf(hv.w, lv.w) + xr.w;
#pragma unroll
      for (int q = 0; q < 4; ++q) { s += v[j * 4 + q]; s2 += v[j * 4 + q] * v[j * 4 + q]; }
    }
    reduce16(s, s2);
    float mu = s * (1.f / 256.f);
    float rs = rsqrtf(s2 * (1.f / 256.f) - mu * mu + 1e-5f);
    float x[16], t1 = 0.f, t2 = 0.f;
#pragma unroll
    for (int j = 0; j < 4; ++j) {
      float4 o;
      o.x = x[j * 4 + 0] = (v[j * 4 + 0] - mu) * rs * nw16[j * 4 + 0] + nb16[j * 4 + 0];
      o.y = x[j * 4 + 1] = (v[j * 4 + 1] - mu) * rs * nw16[j * 4 + 1] + nb16[j * 4 + 1];
      o.z = x[j * 4 + 2] = (v[j * 4 + 2] - mu) * rs * nw16[j * 4 + 2] + nb16[j * 4 + 2];
      o.w = x[j * 4 + 3] = (v[j * 4 + 3] - mu) * rs * nw16[j * 4 + 3] + nb16[j * 4 + 3];
#pragma unroll
      for (int q = 0; q < 4; ++q) { t1 += x[j * 4 + q]; t2 += x[j * 4 + q] * x[j * 4 + q]; }
      *(float4*)&Xc[row * 256 + tx * 4 + 64 * j] = o;
    }
    reduce16(t1, t2);
    float mu2 = t1 * (1.f / 256.f);
    float rs2 = rsqrtf(t2 * (1.f / 256.f) - mu2 * mu2 + 1e-5f);
#pragma unroll
    for (int j = 0; j < 4; ++j) {
      ushort4 ho, lo;
      ushort hh, ll;
#pragma unroll
      for (int q = 0; q < 4; ++q) {
        float y = (x[j * 4 + q] - mu2) * rs2 * fw16[j * 4 + q] + fb16[j * 4 + q];
        split_bf(y, hh, ll);
        ((ushort*)&ho)[q] = hh; ((ushort*)&lo)[q] = ll;
      }
      *(ushort4*)&Hbh[row * 256 + tx * 4 + 64 * j] = ho;
      *(ushort4*)&Hbl[row * 256 + tx * 4 + 64 * j] = lo;
    }
  }
}

// W[K][N] fp32 -> Wt hi/lo [N][K] bf16  (dst offset pre-applied by caller)
__global__ __launch_bounds__(256) void k_wprep(const float* __restrict__ W,
    ushort* __restrict__ Dh, ushort* __restrict__ Dl, int N, int kshift) {
  int idx = blockIdx.x * 256 + threadIdx.x;
  int K = 1 << kshift;
  int n = idx >> kshift, k = idx & (K - 1);
  float x = W[(size_t)k * N + n];
  ushort h, l;
  split_bf(x, h, l);
  Dh[idx] = h; Dl[idx] = l;
}

__global__ __launch_bounds__(256) void k_cat2(float* __restrict__ dst,
    const float* __restrict__ a, int na, const float* __restrict__ b, int nb) {
  int i = blockIdx.x * 256 + threadIdx.x;
  if (i < na) dst[i] = a[i];
  else if (i < na + nb) dst[i] = b[i - na];
}

extern "C" void kernel_launch(void* const* d_in, const int* in_sizes, int n_in,
                              void* d_out, int out_size, void* d_ws, size_t ws_size,
                              hipStream_t stream) {
  const float* slots  = (const float*)d_in[0];
  const float* keep   = (const float*)d_in[1];
  const float* fw_w1  = (const float*)d_in[2];
  const float* fw_b1  = (const float*)d_in[3];
  const float* fw_w2  = (const float*)d_in[4];
  const float* fw_b2  = (const float*)d_in[5];
  const float* fw_lnw = (const float*)d_in[6];
  const float* fw_lnb = (const float*)d_in[7];
  const float* bw_w1  = (const float*)d_in[8];
  const float* bw_b1  = (const float*)d_in[9];
  const float* bw_w2  = (const float*)d_in[10];
  const float* bw_b2  = (const float*)d_in[11];
  const float* bw_lnw = (const float*)d_in[12];
  const float* bw_lnb = (const float*)d_in[13];
  const float* mg_w   = (const float*)d_in[14];
  const float* mg_b   = (const float*)d_in[15];
  const float* nm_w   = (const float*)d_in[16];
  const float* nm_b   = (const float*)d_in[17];
  const float* ffn_lnw= (const float*)d_in[18];
  const float* ffn_lnb= (const float*)d_in[19];
  const float* ffn_w1 = (const float*)d_in[20];
  const float* ffn_b1 = (const float*)d_in[21];
  const float* ffn_w2 = (const float*)d_in[22];
  const float* ffn_b2 = (const float*)d_in[23];
  (void)n_in; (void)out_size;

  const int N = in_sizes[0] / 256;
  float* out = (float*)d_ws ? (float*)d_out : (float*)d_out;
  out = (float*)d_out;

  size_t off = 0;
  char* wsb = (char*)d_ws;
  auto alloc = [&](size_t bytes) -> void* {
    void* p = wsb + off;
    off = (off + bytes + 255) & ~(size_t)255;
    return p;
  };

  struct LayerW {
    ushort *l1h, *l1l, *l2h, *l2l, *mgh, *mgl, *f1h, *f1l, *f2h, *f2l;
    float *bl1, *bl2;
  } lw[2];
  for (int L = 0; L < 2; ++L) {
    lw[L].l1h = (ushort*)alloc(1024 * 256 * 2); lw[L].l1l = (ushort*)alloc(1024 * 256 * 2);
    lw[L].l2h = (ushort*)alloc(512 * 512 * 2);  lw[L].l2l = (ushort*)alloc(512 * 512 * 2);
    lw[L].mgh = (ushort*)alloc(256 * 512 * 2);  lw[L].mgl = (ushort*)alloc(256 * 512 * 2);
    lw[L].f1h = (ushort*)alloc(1024 * 256 * 2); lw[L].f1l = (ushort*)alloc(1024 * 256 * 2);
    lw[L].f2h = (ushort*)alloc(256 * 1024 * 2); lw[L].f2l = (ushort*)alloc(256 * 1024 * 2);
    lw[L].bl1 = (float*)alloc(1024 * 4);
    lw[L].bl2 = (float*)alloc(512 * 4);
  }

  // activation chunking
  size_t remain = ws_size > off ? ws_size - off - 4096 : 0;
  int chunk = N;
  while ((size_t)chunk * 10240 > remain && chunk > 128) chunk >>= 1;

  ushort* H1h = (ushort*)alloc((size_t)chunk * 1024 * 2);
  ushort* H1l = (ushort*)alloc((size_t)chunk * 1024 * 2);
  ushort* Th  = (ushort*)alloc((size_t)chunk * 512 * 2);
  ushort* Tl  = (ushort*)alloc((size_t)chunk * 512 * 2);
  ushort* Fh  = (ushort*)alloc((size_t)chunk * 512 * 2);
  ushort* Fl  = (ushort*)alloc((size_t)chunk * 512 * 2);
  float*  Xc  = (float*)alloc((size_t)chunk * 256 * 4);
  ushort* Hbh = (ushort*)alloc((size_t)chunk * 256 * 2);
  ushort* Hbl = (ushort*)alloc((size_t)chunk * 256 * 2);

  // ---- weight prep (14 tiny launches + bias packs) ----
  for (int L = 0; L < 2; ++L) {
    k_wprep<<<512, 256, 0, stream>>>(fw_w1 + (size_t)L * 256 * 512, lw[L].l1h, lw[L].l1l, 512, 8);
    k_wprep<<<512, 256, 0, stream>>>(bw_w1 + (size_t)L * 256 * 512, lw[L].l1h + 512 * 256, lw[L].l1l + 512 * 256, 512, 8);
    k_wprep<<<512, 256, 0, stream>>>(fw_w2 + (size_t)L * 512 * 256, lw[L].l2h, lw[L].l2l, 256, 9);
    k_wprep<<<512, 256, 0, stream>>>(bw_w2 + (size_t)L * 512 * 256, lw[L].l2h + 256 * 512, lw[L].l2l + 256 * 512, 256, 9);
    k_wprep<<<512, 256, 0, stream>>>(mg_w + (size_t)L * 512 * 256, lw[L].mgh, lw[L].mgl, 256, 9);
    k_wprep<<<1024, 256, 0, stream>>>(ffn_w1 + (size_t)L * 256 * 1024, lw[L].f1h, lw[L].f1l, 1024, 8);
    k_wprep<<<1024, 256, 0, stream>>>(ffn_w2 + (size_t)L * 1024 * 256, lw[L].f2h, lw[L].f2l, 256, 10);
    k_cat2<<<4, 256, 0, stream>>>(lw[L].bl1, fw_b1 + (size_t)L * 512, 512, bw_b1 + (size_t)L * 512, 512);
    k_cat2<<<2, 256, 0, stream>>>(lw[L].bl2, fw_b2 + (size_t)L * 256, 256, bw_b2 + (size_t)L * 256, 256);
  }

  dim3 blk(256);
  for (int L = 0; L < 2; ++L) {
    const float* Xsrc = (L == 0) ? slots : out;
    for (int c0 = 0; c0 < N; c0 += chunk) {
      const float* Xi = Xsrc + (size_t)c0 * 256;
      // 1. lin1 (fw+bw): silu(X @ W1)  -> H1 hl [C][1024]
      k_gemm<8, EPI_SILU, true><<<dim3(chunk / 128, 8), blk, 0, stream>>>(
          Xi, nullptr, 256, 0, 0, lw[L].l1h, lw[L].l1l, lw[L].bl1,
          H1h, H1l, 1024, nullptr, nullptr);
      // 2. lin2 raw: H1 @ W2 -> T hl [C][512]  (branch = by>>1 selects A half)
      k_gemm<16, EPI_RAW, false><<<dim3(chunk / 128, 4), blk, 0, stream>>>(
          H1h, H1l, 1024, 1, 512, lw[L].l2h, lw[L].l2l, lw[L].bl2,
          Th, Tl, 512, nullptr, nullptr);
      // 3. per-branch LN -> F hl [C][512]
      k_ln_hl<<<dim3(chunk / 64, 2), blk, 0, stream>>>(
          Th, Tl, 512, fw_lnw + (size_t)L * 256, fw_lnb + (size_t)L * 256,
          bw_lnw + (size_t)L * 256, bw_lnb + (size_t)L * 256, Fh, Fl, 512);
      // 4. merge: F @ mg_w -> T hl (as Mtmp, ld 256)
      k_gemm<16, EPI_RAW, false><<<dim3(chunk / 128, 2), blk, 0, stream>>>(
          Fh, Fl, 512, 0, 0, lw[L].mgh, lw[L].mgl, mg_b + (size_t)L * 256,
          Th, Tl, 256, nullptr, nullptr);
      // 5. residual + LN + LN -> Xc fp32, Hb hl
      k_mergepost<<<dim3(chunk / 64), blk, 0, stream>>>(
          Th, Tl, Xi, nm_w + (size_t)L * 256, nm_b + (size_t)L * 256,
          ffn_lnw + (size_t)L * 256, ffn_lnb + (size_t)L * 256, Xc, Hbh, Hbl);
      // 6. ffn1: gelu(Hb @ W1) -> Ab hl (alias H1) [C][1024]
      k_gemm<8, EPI_GELU, false><<<dim3(chunk / 128, 8), blk, 0, stream>>>(
          Hbh, Hbl, 256, 0, 0, lw[L].f1h, lw[L].f1l, ffn_b1 + (size_t)L * 1024,
          H1h, H1l, 1024, nullptr, nullptr);
      // 7. ffn2: (Xc + Ab @ W2 + b) * mask -> out fp32
      k_gemm<32, EPI_RES, false><<<dim3(chunk / 128, 2), blk, 0, stream>>>(
          H1h, H1l, 1024, 0, 0, lw[L].f2h, lw[L].f2l, ffn_b2 + (size_t)L * 256,
          out + (size_t)c0 * 256, nullptr, 256, Xc, keep + c0);
    }
  }
}